// Round 15
// baseline (474.405 us; speedup 1.0000x reference)
//
#include <hip/hip_runtime.h>

// PointPillarScatter: scatter (B*P, C) pillar features into dense BEV canvas
// out[b][ch][y][x], zero elsewhere. B=8, C=64, NX=432, NY=496, NZ=1.
//
// v11: read/store TIME-SEPARATED batch-8 register staging.
// Evidence ladder: pure-store kernels = 6.0-6.2 TB/s; r2/r5/r12/r14
// (all with loads or load-waits somewhere near the store stream, or
// plane-strided per-thread walks) = 2.3-3.0 TB/s. Hypothesis (beta):
// reads+writes share in-order vmcnt, so any wait-for-read inside the
// store stream drains store credits -> ~half BW. This kernel: per thread,
// ALL 8 map int4 loads issue first, ALL pf gathers resolve into v[0..7]
// registers (single vmcnt drain), then 8 wave-contiguous 1KB stores with
// no loads/waits between them. Plane-aligned blocks: no div/mod, one
// (b,ch) per block. Alternative hypothesis (alpha): non-constant data
// lines write at half rate -> this kernel stays ~148us and we're at the
// data-write roofline.

#define PPS_NX   432
#define PPS_NY   496
#define PPS_GRID (PPS_NX * PPS_NY)   // 214272
#define PPS_C    64
#define PPS_B    8
#define PPS_U    (PPS_GRID / 4)      // 53568 float4-units per plane

typedef float f32x4 __attribute__((ext_vector_type(4)));

// ---- Kernel 1: init inverse map to -1 (6.86 MB) -------------------------
__global__ void pps_init_map(int4* __restrict__ map4, int n4) {
    int i = blockIdx.x * blockDim.x + threadIdx.x;
    if (i < n4) map4[i] = make_int4(-1, -1, -1, -1);
}

// ---- Kernel 2: scatter pillar indices into the map (32768 x 4 B) --------
__global__ void pps_scatter_idx(const int4* __restrict__ coords,
                                int* __restrict__ map, int P) {
    int p = blockIdx.x * blockDim.x + threadIdx.x;
    if (p >= P) return;
    int4 c = coords[p];   // (batch, z, y, x)
    int pos = c.y + c.z * PPS_NX + c.w;           // in-plane index
    map[c.x * PPS_GRID + pos] = p;
}

// ---- Kernel 3: batch-8 read-then-store, plane-aligned -------------------
// grid = (27 chunks, 512 planes). Block covers f4 [bx*2048, bx*2048+2048)
// of plane (b,ch) (32 KB out). Stores: 8 per thread, each instruction
// 1 KB wave-contiguous, rows 4 KB apart. All loads precede all stores.
__global__ __launch_bounds__(256) void pps_write8(const float* __restrict__ pf,
                                                  const int* __restrict__ map,
                                                  f32x4* __restrict__ out4) {
    const int t     = threadIdx.x;
    const int bx    = blockIdx.x;            // 0..26
    const int plane = blockIdx.y;            // 0..511 = b*64+ch
    const int b     = plane >> 6;
    const int ch    = plane & 63;
    const int base_u = bx * 2048 + t;

    const int4* mrow = (const int4*)(map + (size_t)b * PPS_GRID);

    // Phase 1: all map loads (coalesced 4 KB per row-instruction).
    int4 mm[8];
    #pragma unroll
    for (int r = 0; r < 8; ++r) {
        int u = base_u + r * 256;
        mm[r] = (u < PPS_U) ? mrow[u] : make_int4(-1, -1, -1, -1);
    }

    // Phase 2: resolve all values into registers (pf gathers cluster here;
    // exec-masked scalar loads, ~0.6 occupied pixels per thread expected).
    const float* pfc = pf + ch;
    f32x4 v[8];
    #pragma unroll
    for (int r = 0; r < 8; ++r) {
        f32x4 w = {0.f, 0.f, 0.f, 0.f};
        const int4 m = mm[r];
        if ((m.x & m.y & m.z & m.w) >= 0) {   // any of 4 pixels occupied
            if (m.x >= 0) w.x = pfc[(size_t)m.x * PPS_C];
            if (m.y >= 0) w.y = pfc[(size_t)m.y * PPS_C];
            if (m.z >= 0) w.z = pfc[(size_t)m.z * PPS_C];
            if (m.w >= 0) w.w = pfc[(size_t)m.w * PPS_C];
        }
        v[r] = w;
    }

    // Phase 3: pure store burst -- no loads, no waits between stores.
    f32x4* o = out4 + (size_t)plane * PPS_U + base_u;
    #pragma unroll
    for (int r = 0; r < 8; ++r) {
        int u = base_u + r * 256;
        if (u < PPS_U) o[r * 256] = v[r];    // only tail block masks lanes
    }
}

// ---- Fallback (ws too small): zero + direct scatter ---------------------
__global__ void pps_zero_out(float4* __restrict__ out, long long n4) {
    long long i = (long long)blockIdx.x * blockDim.x + threadIdx.x;
    const long long stride = (long long)gridDim.x * blockDim.x;
    const float4 z = make_float4(0.f, 0.f, 0.f, 0.f);
    for (; i < n4; i += stride) out[i] = z;
}
__global__ void pps_scatter_feat(const float* __restrict__ pf,
                                 const int4* __restrict__ coords,
                                 float* __restrict__ out, int P) {
    int t = blockIdx.x * blockDim.x + threadIdx.x;
    int p = t >> 6;
    if (p >= P) return;
    int ch = t & 63;
    int4 c = coords[p];
    long long pos = (long long)c.x * (long long)(PPS_C * PPS_GRID)
                  + (long long)ch * PPS_GRID
                  + (long long)(c.y + c.z * PPS_NX + c.w);
    out[pos] = pf[t];
}

extern "C" void kernel_launch(void* const* d_in, const int* in_sizes, int n_in,
                              void* d_out, int out_size, void* d_ws, size_t ws_size,
                              hipStream_t stream) {
    const float* pf     = (const float*)d_in[0];
    const int4*  coords = (const int4*)d_in[1];
    float*       out    = (float*)d_out;
    int P = in_sizes[0] / PPS_C;   // B * P_PER = 32768

    const size_t map_bytes = (size_t)PPS_B * PPS_GRID * sizeof(int);
    if (ws_size >= map_bytes) {
        int* map = (int*)d_ws;
        int n4 = PPS_B * (PPS_GRID / 4);              // 428544 int4 entries
        pps_init_map<<<(n4 + 255) / 256, 256, 0, stream>>>((int4*)map, n4);
        pps_scatter_idx<<<(P + 255) / 256, 256, 0, stream>>>(coords, map, P);
        dim3 grid(27, PPS_B * PPS_C);                 // 27 x 512 = 13824 blocks
        pps_write8<<<grid, 256, 0, stream>>>(pf, map, (f32x4*)out);
    } else {
        long long n4 = (long long)out_size / 4;
        pps_zero_out<<<2048, 256, 0, stream>>>((float4*)out, n4);
        int threads = P * PPS_C;
        pps_scatter_feat<<<(threads + 255) / 256, 256, 0, stream>>>(pf, coords, out, P);
    }
}